// Round 4
// baseline (154.628 us; speedup 1.0000x reference)
//
#include <hip/hip_runtime.h>
#include <hip/hip_bf16.h>

// R4: fuse finalize into pairwise via last-block-done (threadfence + counter,
// rocPRIM-style). 2 launches total. row_engine zeroes the counter (stream
// order makes it visible to pairwise). Core math identical to R3 (passed,
// absmax 0.03125). Remaining dur_us is dominated by the harness's 256 MiB
// d_ws poison fill (~43 us) + input restores, visible as fillBufferAligned
// in the profile.

typedef short bf16x8 __attribute__((ext_vector_type(8)));
typedef float f32x4 __attribute__((ext_vector_type(4)));

__device__ __forceinline__ float wave_sum(float v) {
#pragma unroll
  for (int off = 32; off; off >>= 1) v += __shfl_xor(v, off);
  return v;
}

__device__ __forceinline__ unsigned short f2bf(float x) {  // RNE, finite inputs
  union { float f; unsigned u; } v; v.f = x;
  return (unsigned short)((v.u + 0x7fffu + ((v.u >> 16) & 1u)) >> 16);
}
__device__ __forceinline__ float bf2f(unsigned short h) {
  union { float f; unsigned u; } v; v.u = ((unsigned)h) << 16;
  return v.f;
}

// One wave: gumbel-softmax for 16 rows (K=128) -> A-fragments in-register ->
// acc += S @ W^T (16 MFMAs). lgp/nzp pre-offset to (row, part*8): lane
// (r,part) covers columns ks*32 + part*8 + j == exactly its A-fragment slices.
// Cross-lane traffic = softmax denominator only (shfl_xor; no LDS, no barrier).
__device__ __forceinline__ void gumbel_mfma(const float* __restrict__ lgp,
                                            const float* __restrict__ nzp,
                                            const bf16x8 Bf[4][4], f32x4 acc[4]) {
  float e[32];
  float ps = 0.0f;
#pragma unroll
  for (int ks = 0; ks < 4; ++ks) {
#pragma unroll
    for (int h = 0; h < 2; ++h) {
      float4 L = *(const float4*)(lgp + ks * 32 + h * 4);
      float4 U = *(const float4*)(nzp + ks * 32 + h * 4);
      float lv[4] = {L.x, L.y, L.z, L.w};
      float uv[4] = {U.x, U.y, U.z, U.w};
#pragma unroll
      for (int j = 0; j < 4; ++j) {
        float g = -__logf(-__logf(uv[j] + 1e-9f) + 1e-9f);
        float ev = __expf(lv[j] + g);
        e[ks * 8 + h * 4 + j] = ev;
        ps += ev;
      }
    }
  }
  ps += __shfl_xor(ps, 16);
  ps += __shfl_xor(ps, 32);
  float inv = __builtin_amdgcn_rcpf(ps);
#pragma unroll
  for (int ks = 0; ks < 4; ++ks) {
    union { bf16x8 v; unsigned short s[8]; } pk;
#pragma unroll
    for (int j = 0; j < 8; ++j) pk.s[j] = f2bf(e[ks * 8 + j] * inv);
#pragma unroll
    for (int nt = 0; nt < 4; ++nt)
      acc[nt] = __builtin_amdgcn_mfma_f32_16x16x32_bf16(pk.v, Bf[nt][ks], acc[nt], 0, 0, 0);
  }
}

// grid 256 x 256 threads. wid even -> x-type (16 rows of x), wid odd ->
// pair-type (xi,xj in-wave -> denom; bias cancels in the difference).
__global__ __launch_bounds__(256) void row_engine(
    const float* __restrict__ logits, const float* __restrict__ noise_f,
    const float* __restrict__ noise_i, const float* __restrict__ noise_j,
    const float* __restrict__ topic_w, const float* __restrict__ tb,
    const int* __restrict__ ii, const int* __restrict__ jj,
    unsigned short* __restrict__ xb, float* __restrict__ sq,
    float* __restrict__ denomS, int* __restrict__ cnt) {
  if (blockIdx.x == 0 && threadIdx.x == 0) *cnt = 0;  // gate for pairwise_fin
  int w = threadIdx.x >> 6, lane = threadIdx.x & 63;
  int r = lane & 15, part = lane >> 4;
  int wid = blockIdx.x * 4 + w;

  // B fragments (held whole kernel): lane (r,part), step ks:
  // B[k = ks*32 + part*8 + j][n = nt*16 + r] = topic_w[n*128 + k].
  bf16x8 Bf[4][4];
#pragma unroll
  for (int nt = 0; nt < 4; ++nt) {
    const float* wp = topic_w + (nt * 16 + r) * 128 + part * 8;
#pragma unroll
    for (int ks = 0; ks < 4; ++ks) {
      float4 w0 = *(const float4*)(wp + ks * 32);
      float4 w1 = *(const float4*)(wp + ks * 32 + 4);
      union { bf16x8 v; unsigned short s[8]; } pk;
      pk.s[0] = f2bf(w0.x); pk.s[1] = f2bf(w0.y); pk.s[2] = f2bf(w0.z); pk.s[3] = f2bf(w0.w);
      pk.s[4] = f2bf(w1.x); pk.s[5] = f2bf(w1.y); pk.s[6] = f2bf(w1.z); pk.s[7] = f2bf(w1.w);
      Bf[nt][ks] = pk.v;
    }
  }
  int grp = wid >> 1;
  if ((wid & 1) == 0) {
    // x-type: rows g16..g16+15. C-layout: row m = part*4+g, col n = nt*16+r.
    int g16 = grp * 16;
    float tbv[4];
#pragma unroll
    for (int nt = 0; nt < 4; ++nt) tbv[nt] = tb[nt * 16 + r];
    f32x4 acc[4] = {};
    gumbel_mfma(logits + (g16 + r) * 128 + part * 8,
                noise_f + (g16 + r) * 128 + part * 8, Bf, acc);
    float sqp[4] = {0.f, 0.f, 0.f, 0.f};
#pragma unroll
    for (int nt = 0; nt < 4; ++nt)
#pragma unroll
      for (int g = 0; g < 4; ++g) {
        unsigned short hb = f2bf(acc[nt][g] + tbv[nt]);
        xb[(g16 + part * 4 + g) * 64 + nt * 16 + r] = hb;
        float xr = bf2f(hb);  // rounded value -> sq consistent with Gram dot
        sqp[g] += xr * xr;
      }
#pragma unroll
    for (int m = 1; m < 16; m <<= 1)
#pragma unroll
      for (int g = 0; g < 4; ++g) sqp[g] += __shfl_xor(sqp[g], m);
    if (r == 0) {
#pragma unroll
      for (int g = 0; g < 4; ++g) sq[g16 + part * 4 + g] = sqp[g];
    }
  } else {
    // pair-type: batch elems b0..b0+15; denom = 64 + ||xi-xj||^2 (fp32 diff).
    int b0 = grp * 16;
    int rowi = ii[b0 + r], rowj = jj[b0 + r];
    f32x4 ai[4] = {}, aj[4] = {};
    gumbel_mfma(logits + rowi * 128 + part * 8,
                noise_i + (b0 + r) * 128 + part * 8, Bf, ai);
    gumbel_mfma(logits + rowj * 128 + part * 8,
                noise_j + (b0 + r) * 128 + part * 8, Bf, aj);
    float dp[4] = {0.f, 0.f, 0.f, 0.f};
#pragma unroll
    for (int nt = 0; nt < 4; ++nt)
#pragma unroll
      for (int g = 0; g < 4; ++g) {
        float d = ai[nt][g] - aj[nt][g];
        dp[g] += d * d;
      }
#pragma unroll
    for (int m = 1; m < 16; m <<= 1)
#pragma unroll
      for (int g = 0; g < 4; ++g) dp[g] += __shfl_xor(dp[g], m);
    if (r == 0) {
#pragma unroll
      for (int g = 0; g < 4; ++g) denomS[b0 + part * 4 + g] = 64.0f + dp[g];
    }
  }
}

// Triangular pairwise (2080 tiles, bi<=bj), per-wave 64x64 subtile, per-wave
// partial slot, then last-done block performs the entire finalize (no extra
// launch). Counter pre-zeroed by row_engine (stream order).
__global__ __launch_bounds__(256) void pairwise_fin(
    const unsigned short* __restrict__ xbp, const float* __restrict__ sq,
    float* __restrict__ partial, int* __restrict__ cnt,
    const float* __restrict__ pij, const float* __restrict__ denomS,
    float* __restrict__ out) {
  __shared__ float red[4];
  __shared__ int lastFlag;
  int w = threadIdx.x >> 6, lane = threadIdx.x & 63;
  int t = blockIdx.x, bi = 0;
  while (t >= 64 - bi) { t -= 64 - bi; ++bi; }  // uniform scalar decode
  int bj = bi + t;
  int wr = w >> 1, wc = w & 1;
  bool diag = (bi == bj);
  float local = 0.0f;
  if (!(diag && wr > wc)) {  // lower-left wave of a diag block contributes 0
    int R = bi * 128 + wr * 64;
    int C = bj * 128 + wc * 64;
    int r0 = lane & 15, kq = lane >> 4;

    bf16x8 A[4][2], B[4][2];
#pragma unroll
    for (int a = 0; a < 4; ++a)
#pragma unroll
      for (int s = 0; s < 2; ++s) {
        A[a][s] = *(const bf16x8*)(xbp + (R + a * 16 + r0) * 64 + s * 32 + kq * 8);
        B[a][s] = *(const bf16x8*)(xbp + (C + a * 16 + r0) * 64 + s * 32 + kq * 8);
      }
    // sq loads issued before the MFMA chain (independent -> overlap)
    float m1[4][4], nsq[4];
#pragma unroll
    for (int a = 0; a < 4; ++a)
#pragma unroll
      for (int g = 0; g < 4; ++g) m1[a][g] = 1.0f + sq[R + a * 16 + kq * 4 + g];
#pragma unroll
    for (int b = 0; b < 4; ++b) nsq[b] = sq[C + b * 16 + r0];

    f32x4 acc[4][4] = {};
#pragma unroll
    for (int a = 0; a < 4; ++a)
#pragma unroll
      for (int b = 0; b < 4; ++b) {
        acc[a][b] = __builtin_amdgcn_mfma_f32_16x16x32_bf16(A[a][0], B[b][0], acc[a][b], 0, 0, 0);
        acc[a][b] = __builtin_amdgcn_mfma_f32_16x16x32_bf16(A[a][1], B[b][1], acc[a][b], 0, 0, 0);
      }

    if (diag && wr == wc) {  // tile straddling the diagonal: keep r<c only
#pragma unroll
      for (int a = 0; a < 4; ++a)
#pragma unroll
        for (int b = 0; b < 4; ++b)
#pragma unroll
          for (int g = 0; g < 4; ++g) {
            float d = fmaf(-2.0f, acc[a][b][g], m1[a][g] + nsq[b]);
            int rl = a * 16 + kq * 4 + g, cl = b * 16 + r0;
            local += (rl < cl) ? __builtin_amdgcn_rcpf(d) : 0.0f;
          }
    } else {
#pragma unroll
      for (int a = 0; a < 4; ++a)
#pragma unroll
        for (int b = 0; b < 4; ++b)
#pragma unroll
          for (int g = 0; g < 4; ++g) {
            float d = fmaf(-2.0f, acc[a][b][g], m1[a][g] + nsq[b]);
            local += __builtin_amdgcn_rcpf(d);
          }
    }
  }
  local = wave_sum(local);
  if (lane == 0) partial[blockIdx.x * 4 + w] = local;  // every slot written

  // ---- last-block-done finalize ----
  __syncthreads();  // all 4 partial stores drained (vmcnt before barrier)
  if (threadIdx.x == 0) {
    __threadfence();                       // release: partials -> device scope
    int old = atomicAdd(cnt, 1);           // device-scope by default
    lastFlag = (old == 2079);
  }
  __syncthreads();
  if (lastFlag) {
    __threadfence();                       // acquire: see all blocks' partials
    float ps = 0.0f;
    for (int k = threadIdx.x; k < 2080 * 4; k += 256) ps += partial[k];
    ps = wave_sum(ps);
    if (lane == 0) red[w] = ps;
    __syncthreads();
    float part = 2.0f * (red[0] + red[1] + red[2] + red[3]);  // = full sum - 8192
    float lp = __logf(part);
    for (int b = threadIdx.x; b < 8192; b += 256) {
      float p = pij[b];
      out[b] = p * (__logf(p) + __logf(denomS[b]) + lp);
    }
  }
}

extern "C" void kernel_launch(void* const* d_in, const int* in_sizes, int n_in,
                              void* d_out, int out_size, void* d_ws, size_t ws_size,
                              hipStream_t stream) {
  const float* pij     = (const float*)d_in[0];
  const float* noise_f = (const float*)d_in[1];
  const float* noise_i = (const float*)d_in[2];
  const float* noise_j = (const float*)d_in[3];
  const float* logits  = (const float*)d_in[4];
  const float* topic_w = (const float*)d_in[5];
  const float* tb      = (const float*)d_in[6];
  const int*   ii      = (const int*)d_in[7];
  const int*   jj      = (const int*)d_in[8];
  float* out = (float*)d_out;

  char* ws = (char*)ws_size ? (char*)d_ws : (char*)d_ws;
  float* partial     = (float*)ws;                                 // 8320 f32 = 33280 B
  int*   cnt         = (int*)(ws + 33280);                         // done-counter
  unsigned short* xb = (unsigned short*)(ws + 33344);              // 8192*64 bf16 = 1 MB
  float* sq          = (float*)(ws + 33344 + 1048576);             // 8192 f32
  float* denomS      = (float*)(ws + 33344 + 1048576 + 32768);     // 8192 f32

  row_engine<<<256, 256, 0, stream>>>(logits, noise_f, noise_i, noise_j,
                                      topic_w, tb, ii, jj, xb, sq, denomS, cnt);
  pairwise_fin<<<2080, 256, 0, stream>>>(xb, sq, partial, cnt, pij, denomS, out);
}

// Round 5
// 115.821 us; speedup vs baseline: 1.3351x; 1.3351x over previous
//
#include <hip/hip_runtime.h>
#include <hip/hip_bf16.h>

// R5: revert R4's last-block fusion (single-block finalize tail ran ~30-50 us
// at near-zero occupancy with cold L2 after the acquire fence). Back to the
// validated 3-kernel R3 structure, plus fat pairwise blocks: 544 blocks
// (was 2080), each covering one row-band x up-to-4 column tiles with A-frags
// and row-sq loaded once and reused -> attacks the per-block overhead that
// made 2080 skinny blocks run ~85% stalled.

typedef short bf16x8 __attribute__((ext_vector_type(8)));
typedef float f32x4 __attribute__((ext_vector_type(4)));

__device__ __forceinline__ float wave_sum(float v) {
#pragma unroll
  for (int off = 32; off; off >>= 1) v += __shfl_xor(v, off);
  return v;
}

__device__ __forceinline__ unsigned short f2bf(float x) {  // RNE, finite inputs
  union { float f; unsigned u; } v; v.f = x;
  return (unsigned short)((v.u + 0x7fffu + ((v.u >> 16) & 1u)) >> 16);
}
__device__ __forceinline__ float bf2f(unsigned short h) {
  union { float f; unsigned u; } v; v.u = ((unsigned)h) << 16;
  return v.f;
}

// One wave: gumbel-softmax for 16 rows (K=128) -> A-fragments in-register ->
// acc += S @ W^T (16 MFMAs). lgp/nzp pre-offset to (row, part*8): lane
// (r,part) covers columns ks*32 + part*8 + j == exactly its A-fragment slices.
// Cross-lane traffic = softmax denominator only (shfl_xor; no LDS, no barrier).
__device__ __forceinline__ void gumbel_mfma(const float* __restrict__ lgp,
                                            const float* __restrict__ nzp,
                                            const bf16x8 Bf[4][4], f32x4 acc[4]) {
  float e[32];
  float ps = 0.0f;
#pragma unroll
  for (int ks = 0; ks < 4; ++ks) {
#pragma unroll
    for (int h = 0; h < 2; ++h) {
      float4 L = *(const float4*)(lgp + ks * 32 + h * 4);
      float4 U = *(const float4*)(nzp + ks * 32 + h * 4);
      float lv[4] = {L.x, L.y, L.z, L.w};
      float uv[4] = {U.x, U.y, U.z, U.w};
#pragma unroll
      for (int j = 0; j < 4; ++j) {
        float g = -__logf(-__logf(uv[j] + 1e-9f) + 1e-9f);
        float ev = __expf(lv[j] + g);
        e[ks * 8 + h * 4 + j] = ev;
        ps += ev;
      }
    }
  }
  ps += __shfl_xor(ps, 16);
  ps += __shfl_xor(ps, 32);
  float inv = __builtin_amdgcn_rcpf(ps);
#pragma unroll
  for (int ks = 0; ks < 4; ++ks) {
    union { bf16x8 v; unsigned short s[8]; } pk;
#pragma unroll
    for (int j = 0; j < 8; ++j) pk.s[j] = f2bf(e[ks * 8 + j] * inv);
#pragma unroll
    for (int nt = 0; nt < 4; ++nt)
      acc[nt] = __builtin_amdgcn_mfma_f32_16x16x32_bf16(pk.v, Bf[nt][ks], acc[nt], 0, 0, 0);
  }
}

// grid 256 x 256 threads. wid even -> x-type (16 rows of x), wid odd ->
// pair-type (xi,xj in-wave -> denom; bias cancels in the difference).
__global__ __launch_bounds__(256) void row_engine(
    const float* __restrict__ logits, const float* __restrict__ noise_f,
    const float* __restrict__ noise_i, const float* __restrict__ noise_j,
    const float* __restrict__ topic_w, const float* __restrict__ tb,
    const int* __restrict__ ii, const int* __restrict__ jj,
    unsigned short* __restrict__ xb, float* __restrict__ sq,
    float* __restrict__ denomS) {
  int w = threadIdx.x >> 6, lane = threadIdx.x & 63;
  int r = lane & 15, part = lane >> 4;
  int wid = blockIdx.x * 4 + w;

  // B fragments (held whole kernel): lane (r,part), step ks:
  // B[k = ks*32 + part*8 + j][n = nt*16 + r] = topic_w[n*128 + k].
  bf16x8 Bf[4][4];
#pragma unroll
  for (int nt = 0; nt < 4; ++nt) {
    const float* wp = topic_w + (nt * 16 + r) * 128 + part * 8;
#pragma unroll
    for (int ks = 0; ks < 4; ++ks) {
      float4 w0 = *(const float4*)(wp + ks * 32);
      float4 w1 = *(const float4*)(wp + ks * 32 + 4);
      union { bf16x8 v; unsigned short s[8]; } pk;
      pk.s[0] = f2bf(w0.x); pk.s[1] = f2bf(w0.y); pk.s[2] = f2bf(w0.z); pk.s[3] = f2bf(w0.w);
      pk.s[4] = f2bf(w1.x); pk.s[5] = f2bf(w1.y); pk.s[6] = f2bf(w1.z); pk.s[7] = f2bf(w1.w);
      Bf[nt][ks] = pk.v;
    }
  }
  int grp = wid >> 1;
  if ((wid & 1) == 0) {
    // x-type: rows g16..g16+15. C-layout: row m = part*4+g, col n = nt*16+r.
    int g16 = grp * 16;
    float tbv[4];
#pragma unroll
    for (int nt = 0; nt < 4; ++nt) tbv[nt] = tb[nt * 16 + r];
    f32x4 acc[4] = {};
    gumbel_mfma(logits + (g16 + r) * 128 + part * 8,
                noise_f + (g16 + r) * 128 + part * 8, Bf, acc);
    float sqp[4] = {0.f, 0.f, 0.f, 0.f};
#pragma unroll
    for (int nt = 0; nt < 4; ++nt)
#pragma unroll
      for (int g = 0; g < 4; ++g) {
        unsigned short hb = f2bf(acc[nt][g] + tbv[nt]);
        xb[(g16 + part * 4 + g) * 64 + nt * 16 + r] = hb;
        float xr = bf2f(hb);  // rounded value -> sq consistent with Gram dot
        sqp[g] += xr * xr;
      }
#pragma unroll
    for (int m = 1; m < 16; m <<= 1)
#pragma unroll
      for (int g = 0; g < 4; ++g) sqp[g] += __shfl_xor(sqp[g], m);
    if (r == 0) {
#pragma unroll
      for (int g = 0; g < 4; ++g) sq[g16 + part * 4 + g] = sqp[g];
    }
  } else {
    // pair-type: batch elems b0..b0+15; denom = 64 + ||xi-xj||^2 (fp32 diff).
    int b0 = grp * 16;
    int rowi = ii[b0 + r], rowj = jj[b0 + r];
    f32x4 ai[4] = {}, aj[4] = {};
    gumbel_mfma(logits + rowi * 128 + part * 8,
                noise_i + (b0 + r) * 128 + part * 8, Bf, ai);
    gumbel_mfma(logits + rowj * 128 + part * 8,
                noise_j + (b0 + r) * 128 + part * 8, Bf, aj);
    float dp[4] = {0.f, 0.f, 0.f, 0.f};
#pragma unroll
    for (int nt = 0; nt < 4; ++nt)
#pragma unroll
      for (int g = 0; g < 4; ++g) {
        float d = ai[nt][g] - aj[nt][g];
        dp[g] += d * d;
      }
#pragma unroll
    for (int m = 1; m < 16; m <<= 1)
#pragma unroll
      for (int g = 0; g < 4; ++g) dp[g] += __shfl_xor(dp[g], m);
    if (r == 0) {
#pragma unroll
      for (int g = 0; g < 4; ++g) denomS[b0 + part * 4 + g] = 64.0f + dp[g];
    }
  }
}

// Fat-block triangular pairwise: 544 blocks. Block = (row-band bi, chunk of
// <=4 column tiles). A-fragments + row m1 loaded once, reused across the
// chunk; B/nsq per column tile. Per-block LDS reduce -> partial[block].
#define NPAIR_BLOCKS 544
__global__ __launch_bounds__(256) void pairwise(const unsigned short* __restrict__ xbp,
                                                const float* __restrict__ sq,
                                                float* __restrict__ partial) {
  __shared__ float red[4];
  int w = threadIdx.x >> 6, lane = threadIdx.x & 63;
  // decode blockIdx -> (bi, cj0): bi row-band, chunks of 4 over bj in [bi,63]
  int b = blockIdx.x, bi = 0, nch = 16;
  while (b >= nch) { b -= nch; ++bi; nch = (64 - bi + 3) >> 2; }
  int cj0 = bi + (b << 2);
  int wr = w >> 1, wc = w & 1;
  int R = bi * 128 + wr * 64;
  int r0 = lane & 15, kq = lane >> 4;

  bf16x8 A[4][2];
#pragma unroll
  for (int a = 0; a < 4; ++a)
#pragma unroll
    for (int s = 0; s < 2; ++s)
      A[a][s] = *(const bf16x8*)(xbp + (R + a * 16 + r0) * 64 + s * 32 + kq * 8);
  float m1[4][4];
#pragma unroll
  for (int a = 0; a < 4; ++a)
#pragma unroll
    for (int g = 0; g < 4; ++g) m1[a][g] = 1.0f + sq[R + a * 16 + kq * 4 + g];

  float local = 0.0f;
  int bjEnd = min(cj0 + 4, 64);
  for (int bj = cj0; bj < bjEnd; ++bj) {
    bool diagT = (bj == bi);
    if (diagT && wr > wc) continue;  // wave-uniform branch
    int C = bj * 128 + wc * 64;

    bf16x8 B[4][2];
#pragma unroll
    for (int a = 0; a < 4; ++a)
#pragma unroll
      for (int s = 0; s < 2; ++s)
        B[a][s] = *(const bf16x8*)(xbp + (C + a * 16 + r0) * 64 + s * 32 + kq * 8);
    float nsq[4];
#pragma unroll
    for (int q = 0; q < 4; ++q) nsq[q] = sq[C + q * 16 + r0];

    f32x4 acc[4][4] = {};
#pragma unroll
    for (int a = 0; a < 4; ++a)
#pragma unroll
      for (int q = 0; q < 4; ++q) {
        acc[a][q] = __builtin_amdgcn_mfma_f32_16x16x32_bf16(A[a][0], B[q][0], acc[a][q], 0, 0, 0);
        acc[a][q] = __builtin_amdgcn_mfma_f32_16x16x32_bf16(A[a][1], B[q][1], acc[a][q], 0, 0, 0);
      }

    if (diagT && wr == wc) {  // tile straddling the diagonal: keep r<c only
#pragma unroll
      for (int a = 0; a < 4; ++a)
#pragma unroll
        for (int q = 0; q < 4; ++q)
#pragma unroll
          for (int g = 0; g < 4; ++g) {
            float d = fmaf(-2.0f, acc[a][q][g], m1[a][g] + nsq[q]);
            int rl = a * 16 + kq * 4 + g, cl = q * 16 + r0;
            local += (rl < cl) ? __builtin_amdgcn_rcpf(d) : 0.0f;
          }
    } else {
#pragma unroll
      for (int a = 0; a < 4; ++a)
#pragma unroll
        for (int q = 0; q < 4; ++q)
#pragma unroll
          for (int g = 0; g < 4; ++g) {
            float d = fmaf(-2.0f, acc[a][q][g], m1[a][g] + nsq[q]);
            local += __builtin_amdgcn_rcpf(d);
          }
    }
  }
  local = wave_sum(local);
  if (lane == 0) red[w] = local;
  __syncthreads();
  if (threadIdx.x == 0) partial[blockIdx.x] = red[0] + red[1] + red[2] + red[3];
}

// part = 2 * sum_{m<n} rcp = (ref's full sum incl. diagonal) - 8192 exactly.
__global__ __launch_bounds__(256) void finalize(const float* __restrict__ pij,
                                                const float* __restrict__ denomS,
                                                const float* __restrict__ partial,
                                                float* __restrict__ out) {
  __shared__ float red[4];
  int tid = threadIdx.x, w = tid >> 6, lane = tid & 63;
  float ps = 0.0f;
  for (int k = tid; k < NPAIR_BLOCKS; k += 256) ps += partial[k];
  ps = wave_sum(ps);
  if (lane == 0) red[w] = ps;
  __syncthreads();
  float part = 2.0f * (red[0] + red[1] + red[2] + red[3]);
  int b = blockIdx.x * 256 + tid;
  float p = pij[b];
  out[b] = p * (__logf(p) + __logf(denomS[b]) + __logf(part));
}

extern "C" void kernel_launch(void* const* d_in, const int* in_sizes, int n_in,
                              void* d_out, int out_size, void* d_ws, size_t ws_size,
                              hipStream_t stream) {
  const float* pij     = (const float*)d_in[0];
  const float* noise_f = (const float*)d_in[1];
  const float* noise_i = (const float*)d_in[2];
  const float* noise_j = (const float*)d_in[3];
  const float* logits  = (const float*)d_in[4];
  const float* topic_w = (const float*)d_in[5];
  const float* tb      = (const float*)d_in[6];
  const int*   ii      = (const int*)d_in[7];
  const int*   jj      = (const int*)d_in[8];
  float* out = (float*)d_out;

  char* ws = (char*)d_ws;
  float* partial     = (float*)ws;                               // 544 f32
  unsigned short* xb = (unsigned short*)(ws + 8192);             // 8192*64 bf16 = 1 MB
  float* sq          = (float*)(ws + 8192 + 1048576);            // 8192 f32
  float* denomS      = (float*)(ws + 8192 + 1048576 + 32768);    // 8192 f32

  row_engine<<<256, 256, 0, stream>>>(logits, noise_f, noise_i, noise_j,
                                      topic_w, tb, ii, jj, xb, sq, denomS);
  pairwise<<<NPAIR_BLOCKS, 256, 0, stream>>>(xb, sq, partial);
  finalize<<<32, 256, 0, stream>>>(pij, denomS, partial, out);
}

// Round 6
// 113.213 us; speedup vs baseline: 1.3658x; 1.0230x over previous
//
#include <hip/hip_runtime.h>
#include <hip/hip_bf16.h>

// R6: software-pipeline pairwise's bj loop (double-buffered B/nsq prefetch).
// R5 analysis: pairwise ~25-30 us wall vs ~3 us busy floor (rcp-rate) with
// FETCH_SIZE only 4.3 MB -> VMEM-latency stall per iteration (L2 cold after
// inter-kernel flush), not BW. Prefetch hides the next tile's ~300-900 cyc
// load under the current tile's ~1050 cyc MFMA+epilogue. Everything else
// identical to R5 (passed, absmax 0.03125, 115.8 us).

typedef short bf16x8 __attribute__((ext_vector_type(8)));
typedef float f32x4 __attribute__((ext_vector_type(4)));

__device__ __forceinline__ float wave_sum(float v) {
#pragma unroll
  for (int off = 32; off; off >>= 1) v += __shfl_xor(v, off);
  return v;
}

__device__ __forceinline__ unsigned short f2bf(float x) {  // RNE, finite inputs
  union { float f; unsigned u; } v; v.f = x;
  return (unsigned short)((v.u + 0x7fffu + ((v.u >> 16) & 1u)) >> 16);
}
__device__ __forceinline__ float bf2f(unsigned short h) {
  union { float f; unsigned u; } v; v.u = ((unsigned)h) << 16;
  return v.f;
}

// One wave: gumbel-softmax for 16 rows (K=128) -> A-fragments in-register ->
// acc += S @ W^T (16 MFMAs). lgp/nzp pre-offset to (row, part*8): lane
// (r,part) covers columns ks*32 + part*8 + j == exactly its A-fragment slices.
// Cross-lane traffic = softmax denominator only (shfl_xor; no LDS, no barrier).
__device__ __forceinline__ void gumbel_mfma(const float* __restrict__ lgp,
                                            const float* __restrict__ nzp,
                                            const bf16x8 Bf[4][4], f32x4 acc[4]) {
  float e[32];
  float ps = 0.0f;
#pragma unroll
  for (int ks = 0; ks < 4; ++ks) {
#pragma unroll
    for (int h = 0; h < 2; ++h) {
      float4 L = *(const float4*)(lgp + ks * 32 + h * 4);
      float4 U = *(const float4*)(nzp + ks * 32 + h * 4);
      float lv[4] = {L.x, L.y, L.z, L.w};
      float uv[4] = {U.x, U.y, U.z, U.w};
#pragma unroll
      for (int j = 0; j < 4; ++j) {
        float g = -__logf(-__logf(uv[j] + 1e-9f) + 1e-9f);
        float ev = __expf(lv[j] + g);
        e[ks * 8 + h * 4 + j] = ev;
        ps += ev;
      }
    }
  }
  ps += __shfl_xor(ps, 16);
  ps += __shfl_xor(ps, 32);
  float inv = __builtin_amdgcn_rcpf(ps);
#pragma unroll
  for (int ks = 0; ks < 4; ++ks) {
    union { bf16x8 v; unsigned short s[8]; } pk;
#pragma unroll
    for (int j = 0; j < 8; ++j) pk.s[j] = f2bf(e[ks * 8 + j] * inv);
#pragma unroll
    for (int nt = 0; nt < 4; ++nt)
      acc[nt] = __builtin_amdgcn_mfma_f32_16x16x32_bf16(pk.v, Bf[nt][ks], acc[nt], 0, 0, 0);
  }
}

// grid 256 x 256 threads. wid even -> x-type (16 rows of x), wid odd ->
// pair-type (xi,xj in-wave -> denom; bias cancels in the difference).
__global__ __launch_bounds__(256) void row_engine(
    const float* __restrict__ logits, const float* __restrict__ noise_f,
    const float* __restrict__ noise_i, const float* __restrict__ noise_j,
    const float* __restrict__ topic_w, const float* __restrict__ tb,
    const int* __restrict__ ii, const int* __restrict__ jj,
    unsigned short* __restrict__ xb, float* __restrict__ sq,
    float* __restrict__ denomS) {
  int w = threadIdx.x >> 6, lane = threadIdx.x & 63;
  int r = lane & 15, part = lane >> 4;
  int wid = blockIdx.x * 4 + w;

  // B fragments (held whole kernel): lane (r,part), step ks:
  // B[k = ks*32 + part*8 + j][n = nt*16 + r] = topic_w[n*128 + k].
  bf16x8 Bf[4][4];
#pragma unroll
  for (int nt = 0; nt < 4; ++nt) {
    const float* wp = topic_w + (nt * 16 + r) * 128 + part * 8;
#pragma unroll
    for (int ks = 0; ks < 4; ++ks) {
      float4 w0 = *(const float4*)(wp + ks * 32);
      float4 w1 = *(const float4*)(wp + ks * 32 + 4);
      union { bf16x8 v; unsigned short s[8]; } pk;
      pk.s[0] = f2bf(w0.x); pk.s[1] = f2bf(w0.y); pk.s[2] = f2bf(w0.z); pk.s[3] = f2bf(w0.w);
      pk.s[4] = f2bf(w1.x); pk.s[5] = f2bf(w1.y); pk.s[6] = f2bf(w1.z); pk.s[7] = f2bf(w1.w);
      Bf[nt][ks] = pk.v;
    }
  }
  int grp = wid >> 1;
  if ((wid & 1) == 0) {
    // x-type: rows g16..g16+15. C-layout: row m = part*4+g, col n = nt*16+r.
    int g16 = grp * 16;
    float tbv[4];
#pragma unroll
    for (int nt = 0; nt < 4; ++nt) tbv[nt] = tb[nt * 16 + r];
    f32x4 acc[4] = {};
    gumbel_mfma(logits + (g16 + r) * 128 + part * 8,
                noise_f + (g16 + r) * 128 + part * 8, Bf, acc);
    float sqp[4] = {0.f, 0.f, 0.f, 0.f};
#pragma unroll
    for (int nt = 0; nt < 4; ++nt)
#pragma unroll
      for (int g = 0; g < 4; ++g) {
        unsigned short hb = f2bf(acc[nt][g] + tbv[nt]);
        xb[(g16 + part * 4 + g) * 64 + nt * 16 + r] = hb;
        float xr = bf2f(hb);  // rounded value -> sq consistent with Gram dot
        sqp[g] += xr * xr;
      }
#pragma unroll
    for (int m = 1; m < 16; m <<= 1)
#pragma unroll
      for (int g = 0; g < 4; ++g) sqp[g] += __shfl_xor(sqp[g], m);
    if (r == 0) {
#pragma unroll
      for (int g = 0; g < 4; ++g) sq[g16 + part * 4 + g] = sqp[g];
    }
  } else {
    // pair-type: batch elems b0..b0+15; denom = 64 + ||xi-xj||^2 (fp32 diff).
    int b0 = grp * 16;
    int rowi = ii[b0 + r], rowj = jj[b0 + r];
    f32x4 ai[4] = {}, aj[4] = {};
    gumbel_mfma(logits + rowi * 128 + part * 8,
                noise_i + (b0 + r) * 128 + part * 8, Bf, ai);
    gumbel_mfma(logits + rowj * 128 + part * 8,
                noise_j + (b0 + r) * 128 + part * 8, Bf, aj);
    float dp[4] = {0.f, 0.f, 0.f, 0.f};
#pragma unroll
    for (int nt = 0; nt < 4; ++nt)
#pragma unroll
      for (int g = 0; g < 4; ++g) {
        float d = ai[nt][g] - aj[nt][g];
        dp[g] += d * d;
      }
#pragma unroll
    for (int m = 1; m < 16; m <<= 1)
#pragma unroll
      for (int g = 0; g < 4; ++g) dp[g] += __shfl_xor(dp[g], m);
    if (r == 0) {
#pragma unroll
      for (int g = 0; g < 4; ++g) denomS[b0 + part * 4 + g] = 64.0f + dp[g];
    }
  }
}

// Fat-block triangular pairwise, software-pipelined: 544 blocks, block =
// (row-band bi, chunk of <=4 column tiles). A-frags + m1 loaded once; B/nsq
// for tile bj+1 prefetched during tile bj's MFMA+epilogue (double buffer).
#define NPAIR_BLOCKS 544
__global__ __launch_bounds__(256) void pairwise(const unsigned short* __restrict__ xbp,
                                                const float* __restrict__ sq,
                                                float* __restrict__ partial) {
  __shared__ float red[4];
  int w = threadIdx.x >> 6, lane = threadIdx.x & 63;
  // decode blockIdx -> (bi, cj0): bi row-band, chunks of 4 over bj in [bi,63]
  int b = blockIdx.x, bi = 0, nch = 16;
  while (b >= nch) { b -= nch; ++bi; nch = (64 - bi + 3) >> 2; }
  int cj0 = bi + (b << 2);
  int wr = w >> 1, wc = w & 1;
  int R = bi * 128 + wr * 64;
  int r0 = lane & 15, kq = lane >> 4;

  bf16x8 A[4][2];
#pragma unroll
  for (int a = 0; a < 4; ++a)
#pragma unroll
    for (int s = 0; s < 2; ++s)
      A[a][s] = *(const bf16x8*)(xbp + (R + a * 16 + r0) * 64 + s * 32 + kq * 8);
  float m1[4][4];
#pragma unroll
  for (int a = 0; a < 4; ++a)
#pragma unroll
    for (int g = 0; g < 4; ++g) m1[a][g] = 1.0f + sq[R + a * 16 + kq * 4 + g];

  float local = 0.0f;
  int bjEnd = min(cj0 + 4, 64);
  int bj = cj0;
  if (cj0 == bi && wr > wc) ++bj;  // lower-left wave of the diag tile: skip it
  if (bj < bjEnd) {
    // prologue: load tile bj
    bf16x8 Bc[4][2];
    float nsqc[4];
    {
      int C = bj * 128 + wc * 64;
#pragma unroll
      for (int a = 0; a < 4; ++a)
#pragma unroll
        for (int s = 0; s < 2; ++s)
          Bc[a][s] = *(const bf16x8*)(xbp + (C + a * 16 + r0) * 64 + s * 32 + kq * 8);
#pragma unroll
      for (int q = 0; q < 4; ++q) nsqc[q] = sq[C + q * 16 + r0];
    }
    for (; bj < bjEnd; ++bj) {
      bool hasNext = (bj + 1) < bjEnd;
      bf16x8 Bn[4][2];
      float nsqn[4];
      if (hasNext) {  // issue next tile's loads before this tile's compute
        int Cn = (bj + 1) * 128 + wc * 64;
#pragma unroll
        for (int a = 0; a < 4; ++a)
#pragma unroll
          for (int s = 0; s < 2; ++s)
            Bn[a][s] = *(const bf16x8*)(xbp + (Cn + a * 16 + r0) * 64 + s * 32 + kq * 8);
#pragma unroll
        for (int q = 0; q < 4; ++q) nsqn[q] = sq[Cn + q * 16 + r0];
      }

      f32x4 acc[4][4] = {};
#pragma unroll
      for (int a = 0; a < 4; ++a)
#pragma unroll
        for (int q = 0; q < 4; ++q) {
          acc[a][q] = __builtin_amdgcn_mfma_f32_16x16x32_bf16(A[a][0], Bc[q][0], acc[a][q], 0, 0, 0);
          acc[a][q] = __builtin_amdgcn_mfma_f32_16x16x32_bf16(A[a][1], Bc[q][1], acc[a][q], 0, 0, 0);
        }

      if (bj == bi && wr == wc) {  // tile straddling the diagonal: r<c only
#pragma unroll
        for (int a = 0; a < 4; ++a)
#pragma unroll
          for (int q = 0; q < 4; ++q)
#pragma unroll
            for (int g = 0; g < 4; ++g) {
              float d = fmaf(-2.0f, acc[a][q][g], m1[a][g] + nsqc[q]);
              int rl = a * 16 + kq * 4 + g, cl = q * 16 + r0;
              local += (rl < cl) ? __builtin_amdgcn_rcpf(d) : 0.0f;
            }
      } else {
#pragma unroll
        for (int a = 0; a < 4; ++a)
#pragma unroll
          for (int q = 0; q < 4; ++q)
#pragma unroll
            for (int g = 0; g < 4; ++g) {
              float d = fmaf(-2.0f, acc[a][q][g], m1[a][g] + nsqc[q]);
              local += __builtin_amdgcn_rcpf(d);
            }
      }

      if (hasNext) {
#pragma unroll
        for (int a = 0; a < 4; ++a)
#pragma unroll
          for (int s = 0; s < 2; ++s) Bc[a][s] = Bn[a][s];
#pragma unroll
        for (int q = 0; q < 4; ++q) nsqc[q] = nsqn[q];
      }
    }
  }
  local = wave_sum(local);
  if (lane == 0) red[w] = local;
  __syncthreads();
  if (threadIdx.x == 0) partial[blockIdx.x] = red[0] + red[1] + red[2] + red[3];
}

// part = 2 * sum_{m<n} rcp = (ref's full sum incl. diagonal) - 8192 exactly.
__global__ __launch_bounds__(256) void finalize(const float* __restrict__ pij,
                                                const float* __restrict__ denomS,
                                                const float* __restrict__ partial,
                                                float* __restrict__ out) {
  __shared__ float red[4];
  int tid = threadIdx.x, w = tid >> 6, lane = tid & 63;
  float ps = 0.0f;
  for (int k = tid; k < NPAIR_BLOCKS; k += 256) ps += partial[k];
  ps = wave_sum(ps);
  if (lane == 0) red[w] = ps;
  __syncthreads();
  float part = 2.0f * (red[0] + red[1] + red[2] + red[3]);
  int b = blockIdx.x * 256 + tid;
  float p = pij[b];
  out[b] = p * (__logf(p) + __logf(denomS[b]) + __logf(part));
}

extern "C" void kernel_launch(void* const* d_in, const int* in_sizes, int n_in,
                              void* d_out, int out_size, void* d_ws, size_t ws_size,
                              hipStream_t stream) {
  const float* pij     = (const float*)d_in[0];
  const float* noise_f = (const float*)d_in[1];
  const float* noise_i = (const float*)d_in[2];
  const float* noise_j = (const float*)d_in[3];
  const float* logits  = (const float*)d_in[4];
  const float* topic_w = (const float*)d_in[5];
  const float* tb      = (const float*)d_in[6];
  const int*   ii      = (const int*)d_in[7];
  const int*   jj      = (const int*)d_in[8];
  float* out = (float*)d_out;

  char* ws = (char*)d_ws;
  float* partial     = (float*)ws;                               // 544 f32
  unsigned short* xb = (unsigned short*)(ws + 8192);             // 8192*64 bf16 = 1 MB
  float* sq          = (float*)(ws + 8192 + 1048576);            // 8192 f32
  float* denomS      = (float*)(ws + 8192 + 1048576 + 32768);    // 8192 f32

  row_engine<<<256, 256, 0, stream>>>(logits, noise_f, noise_i, noise_j,
                                      topic_w, tb, ii, jj, xb, sq, denomS);
  pairwise<<<NPAIR_BLOCKS, 256, 0, stream>>>(xb, sq, partial);
  finalize<<<32, 256, 0, stream>>>(pij, denomS, partial, out);
}